// Round 4
// baseline (57.618 us; speedup 1.0000x reference)
//
#include <hip/hip_runtime.h>
#include <hip/hip_bf16.h>

typedef float  f32x4  __attribute__((ext_vector_type(4)));
typedef short  s16x4  __attribute__((ext_vector_type(4)));
typedef short  s16x8  __attribute__((ext_vector_type(8)));
typedef __bf16 bf16x8 __attribute__((ext_vector_type(8)));

#define DEVI __device__ __forceinline__

DEVI short f2bf(float f) {
    unsigned u = __builtin_bit_cast(unsigned, f);
    u += 0x8000u;
    return (short)(u >> 16);
}
DEVI float bf2f(short s) {
    return __builtin_bit_cast(float, ((unsigned)(unsigned short)s) << 16);
}

DEVI float fast_exp2(float x) {
#if defined(__HIP_DEVICE_COMPILE__) && __has_builtin(__builtin_amdgcn_exp2f)
    return __builtin_amdgcn_exp2f(x);
#else
    return exp2f(x);
#endif
}

DEVI f32x4 mfma32(s16x8 a, s16x8 b, f32x4 c) {
#if defined(__HIP_DEVICE_COMPILE__) && __has_builtin(__builtin_amdgcn_mfma_f32_16x16x32_bf16)
    return __builtin_amdgcn_mfma_f32_16x16x32_bf16(
        __builtin_bit_cast(bf16x8, a), __builtin_bit_cast(bf16x8, b), c, 0, 0, 0);
#else
    asm volatile("v_mfma_f32_16x16x32_bf16 %0, %1, %2, %0" : "+v"(c) : "v"(a), "v"(b));
    return c;
#endif
}

DEVI f32x4 mfma16(s16x4 a, s16x4 b, f32x4 c) {
#if defined(__HIP_DEVICE_COMPILE__) && __has_builtin(__builtin_amdgcn_mfma_f32_16x16x16bf16_1k)
    return __builtin_amdgcn_mfma_f32_16x16x16bf16_1k(a, b, c, 0, 0, 0);
#else
    asm volatile("v_mfma_f32_16x16x16_bf16 %0, %1, %2, %0" : "+v"(c) : "v"(a), "v"(b));
    return c;
#endif
}

// -------------------------------------------------------------------------
// Kernel 1: QKV projection via MFMA.
// 256 blocks (b x 64-l tile) x 512 threads (8 waves).
// LDS: X^T tile [l][c] bf16, XOR-swizzled (16B slots). Same x-fragment regs
// serve as B-operand for Q/K (D = W X -> [o][l]) and A-operand for V
// (D = X^T W^T -> [l][o]) so both output layouts store vectorized.
// Wave w: o-rows [16(w&3), +16), l-frags {2(w>>2), 2(w>>2)+1}.
//   Qg/Kg: [4][4096][64] bf16 (Q pre-scaled by log2(e)/8)
//   Vtg:   [4][64][4096] bf16
// -------------------------------------------------------------------------
__global__ __launch_bounds__(512) void qkv_proj(
    const float* __restrict__ x,
    const float* __restrict__ wq, const float* __restrict__ bq,
    const float* __restrict__ wk, const float* __restrict__ bk,
    const float* __restrict__ wv, const float* __restrict__ bv,
    short* __restrict__ Qg, short* __restrict__ Kg, short* __restrict__ Vtg)
{
    __shared__ short Xt[64 * 64];   // [l][c], slot-swizzled

    const int b  = blockIdx.x >> 6;
    const int l0 = (blockIdx.x & 63) * 64;
    const int t  = threadIdx.x;
    const float QS = 0.18033688011112042f;   // log2(e)/sqrt(64)

    // stage x^T: thread -> column c = t&63, 8 l-values. Conflict-free b16
    // writes (64 lanes hit all 32 banks, pairs share a dword).
    {
        const int c  = t & 63;
        const int lh = (t >> 6) * 8;
        const float* xr = x + ((size_t)b * 64 + c) * 4096 + l0 + lh;
        const float4 x0 = *reinterpret_cast<const float4*>(xr);
        const float4 x1 = *reinterpret_cast<const float4*>(xr + 4);
        float xv[8] = {x0.x, x0.y, x0.z, x0.w, x1.x, x1.y, x1.z, x1.w};
        #pragma unroll
        for (int i = 0; i < 8; ++i) {
            const int l = lh + i;
            Xt[l * 64 + (((c >> 3) ^ (l & 7)) * 8) + (c & 7)] = f2bf(xv[i]);
        }
    }

    const int lane = t & 63, w = t >> 6;
    const int g = lane >> 4, col = lane & 15;
    const int o0 = (w & 3) * 16;
    const int h  = w >> 2;

    // W fragments from global (L2-hot): lane holds W[o0+col][8g+32kc .. +8)
    s16x8 wqf[2], wkf[2], wvf[2];
    #pragma unroll
    for (int kc = 0; kc < 2; ++kc) {
        const int cb = 8 * g + 32 * kc;
        const float4 q0 = *reinterpret_cast<const float4*>(wq + (o0 + col) * 64 + cb);
        const float4 q1 = *reinterpret_cast<const float4*>(wq + (o0 + col) * 64 + cb + 4);
        const float4 k0 = *reinterpret_cast<const float4*>(wk + (o0 + col) * 64 + cb);
        const float4 k1 = *reinterpret_cast<const float4*>(wk + (o0 + col) * 64 + cb + 4);
        const float4 v0 = *reinterpret_cast<const float4*>(wv + (o0 + col) * 64 + cb);
        const float4 v1 = *reinterpret_cast<const float4*>(wv + (o0 + col) * 64 + cb + 4);
        wqf[kc][0] = f2bf(q0.x * QS); wqf[kc][1] = f2bf(q0.y * QS);
        wqf[kc][2] = f2bf(q0.z * QS); wqf[kc][3] = f2bf(q0.w * QS);
        wqf[kc][4] = f2bf(q1.x * QS); wqf[kc][5] = f2bf(q1.y * QS);
        wqf[kc][6] = f2bf(q1.z * QS); wqf[kc][7] = f2bf(q1.w * QS);
        wkf[kc][0] = f2bf(k0.x); wkf[kc][1] = f2bf(k0.y);
        wkf[kc][2] = f2bf(k0.z); wkf[kc][3] = f2bf(k0.w);
        wkf[kc][4] = f2bf(k1.x); wkf[kc][5] = f2bf(k1.y);
        wkf[kc][6] = f2bf(k1.z); wkf[kc][7] = f2bf(k1.w);
        wvf[kc][0] = f2bf(v0.x); wvf[kc][1] = f2bf(v0.y);
        wvf[kc][2] = f2bf(v0.z); wvf[kc][3] = f2bf(v0.w);
        wvf[kc][4] = f2bf(v1.x); wvf[kc][5] = f2bf(v1.y);
        wvf[kc][6] = f2bf(v1.z); wvf[kc][7] = f2bf(v1.w);
    }
    const f32x4 bq4 = *reinterpret_cast<const f32x4*>(bq + o0 + 4 * g);
    const f32x4 bk4 = *reinterpret_cast<const f32x4*>(bk + o0 + 4 * g);
    const float bvs = bv[o0 + col];

    __syncthreads();

    #pragma unroll
    for (int li = 0; li < 2; ++li) {
        const int lt  = 2 * h + li;
        const int row = lt * 16 + col;
        const s16x8 xf0 = *reinterpret_cast<const s16x8*>(
            &Xt[row * 64 + ((g ^ (row & 7)) * 8)]);
        const s16x8 xf1 = *reinterpret_cast<const s16x8*>(
            &Xt[row * 64 + (((g + 4) ^ (row & 7)) * 8)]);

        f32x4 qa = bq4 * QS;
        qa = mfma32(wqf[0], xf0, qa);
        qa = mfma32(wqf[1], xf1, qa);
        f32x4 ka = bk4;
        ka = mfma32(wkf[0], xf0, ka);
        ka = mfma32(wkf[1], xf1, ka);
        f32x4 va = {bvs, bvs, bvs, bvs};
        va = mfma32(xf0, wvf[0], va);
        va = mfma32(xf1, wvf[1], va);

        // Q/K: D[o][l] -> lane: col=l, rows o = o0+4g+r
        s16x4 qs, ks;
        #pragma unroll
        for (int r = 0; r < 4; ++r) { qs[r] = f2bf(qa[r]); ks[r] = f2bf(ka[r]); }
        const size_t qkbase = ((size_t)b * 4096 + l0 + row) * 64 + o0 + 4 * g;
        *reinterpret_cast<s16x4*>(Qg + qkbase) = qs;
        *reinterpret_cast<s16x4*>(Kg + qkbase) = ks;

        // V: D[l][o] -> lane: col=o, rows l = lt*16+4g+r
        s16x4 vs;
        #pragma unroll
        for (int r = 0; r < 4; ++r) vs[r] = f2bf(va[r]);
        *reinterpret_cast<s16x4*>(
            Vtg + ((size_t)b * 64 + o0 + col) * 4096 + l0 + lt * 16 + 4 * g) = vs;
    }
}

// -------------------------------------------------------------------------
// Kernel 2: flash attention partials, 32 q-rows per wave.
// 512 blocks = 4 b x 16 q-tiles(256 rows) x 8 KV-splits(512 rows).
// 8 waves x 32q; per 64-row KV tile: coalesced load -> regs -> swizzled LDS
// (double-buffered, ONE barrier/tile). K/V fragments amortized over 2 q-
// fragments -> LDS read traffic halved vs round 3.
// -------------------------------------------------------------------------
__global__ __launch_bounds__(512, 4) void attn_part(
    const short* __restrict__ Qg, const short* __restrict__ Kg,
    const short* __restrict__ Vtg,
    short* __restrict__ PO, float* __restrict__ PM, float* __restrict__ PL)
{
    __shared__ short Klds[2][64 * 64];
    __shared__ short Vlds[2][64 * 64];

    // XCD-bijective swizzle: each XCD -> one batch, 4 KV-splits (~1MB in L2)
    const int bid = blockIdx.x;
    const int wid = (bid & 7) * 64 + (bid >> 3);
    const int b   = wid >> 7;
    const int sp  = (wid >> 4) & 7;
    const int qt  = wid & 15;

    const int t    = threadIdx.x;
    const int w    = t >> 6;
    const int lane = t & 63;
    const int g    = lane >> 4;
    const int col  = lane & 15;

    const int qbase = qt * 256 + w * 32;

    s16x8 qf[2][2];
    #pragma unroll
    for (int qb = 0; qb < 2; ++qb) {
        const short* qp = Qg + ((size_t)b * 4096 + qbase + qb * 16 + col) * 64 + 8 * g;
        qf[qb][0] = *reinterpret_cast<const s16x8*>(qp);
        qf[qb][1] = *reinterpret_cast<const s16x8*>(qp + 32);
    }

    const short* Kb = Kg  + ((size_t)b * 4096 + sp * 512) * 64;
    const short* Vb = Vtg + (size_t)b * 64 * 4096 + sp * 512;

    const int sr  = t >> 3;
    const int sc  = t & 7;
    const int swz = (sc ^ (sr & 7)) * 8;
    const short* kg = Kb + sr * 64 + sc * 8;
    const short* vg = Vb + (size_t)sr * 4096 + sc * 8;

    s16x8 kreg = *reinterpret_cast<const s16x8*>(kg);
    s16x8 vreg = *reinterpret_cast<const s16x8*>(vg);
    *reinterpret_cast<s16x8*>(&Klds[0][sr * 64 + swz]) = kreg;
    *reinterpret_cast<s16x8*>(&Vlds[0][sr * 64 + swz]) = vreg;
    __syncthreads();

    f32x4 oacc[4][2] = {};
    float m0 = -1e30f, m1 = -1e30f, ls0 = 0.0f, ls1 = 0.0f;

    #pragma unroll 2
    for (int tt = 0; tt < 8; ++tt) {
        const int cur = tt & 1;
        if (tt < 7) {
            kreg = *reinterpret_cast<const s16x8*>(kg + (size_t)(tt + 1) * 64 * 64);
            vreg = *reinterpret_cast<const s16x8*>(vg + (tt + 1) * 64);
        }

        // --- S^T = K Q^T : [jt][qb] ---
        f32x4 sf[4][2] = {};
        #pragma unroll
        for (int jt = 0; jt < 4; ++jt) {
            const int r = jt * 16 + col;
            const s16x8 a0 = *reinterpret_cast<const s16x8*>(
                &Klds[cur][r * 64 + ((g ^ (r & 7)) * 8)]);
            const s16x8 a1 = *reinterpret_cast<const s16x8*>(
                &Klds[cur][r * 64 + (((g + 4) ^ (r & 7)) * 8)]);
            sf[jt][0] = mfma32(a0, qf[0][0], sf[jt][0]);
            sf[jt][0] = mfma32(a1, qf[0][1], sf[jt][0]);
            sf[jt][1] = mfma32(a0, qf[1][0], sf[jt][1]);
            sf[jt][1] = mfma32(a1, qf[1][1], sf[jt][1]);
        }

        // --- online softmax (exp2 domain), defer-max thr 8 ---
        float mx0 = fmaxf(
            fmaxf(fmaxf(fmaxf(sf[0][0][0], sf[0][0][1]), fmaxf(sf[0][0][2], sf[0][0][3])),
                  fmaxf(fmaxf(sf[1][0][0], sf[1][0][1]), fmaxf(sf[1][0][2], sf[1][0][3]))),
            fmaxf(fmaxf(fmaxf(sf[2][0][0], sf[2][0][1]), fmaxf(sf[2][0][2], sf[2][0][3])),
                  fmaxf(fmaxf(sf[3][0][0], sf[3][0][1]), fmaxf(sf[3][0][2], sf[3][0][3]))));
        float mx1 = fmaxf(
            fmaxf(fmaxf(fmaxf(sf[0][1][0], sf[0][1][1]), fmaxf(sf[0][1][2], sf[0][1][3])),
                  fmaxf(fmaxf(sf[1][1][0], sf[1][1][1]), fmaxf(sf[1][1][2], sf[1][1][3]))),
            fmaxf(fmaxf(fmaxf(sf[2][1][0], sf[2][1][1]), fmaxf(sf[2][1][2], sf[2][1][3])),
                  fmaxf(fmaxf(sf[3][1][0], sf[3][1][1]), fmaxf(sf[3][1][2], sf[3][1][3]))));
        mx0 = fmaxf(mx0, __shfl_xor(mx0, 16)); mx0 = fmaxf(mx0, __shfl_xor(mx0, 32));
        mx1 = fmaxf(mx1, __shfl_xor(mx1, 16)); mx1 = fmaxf(mx1, __shfl_xor(mx1, 32));

        if (!__all(fmaxf(mx0 - m0, mx1 - m1) <= 8.0f)) {
            const float n0 = fmaxf(m0, mx0), n1 = fmaxf(m1, mx1);
            const float a0 = fast_exp2(m0 - n0), a1 = fast_exp2(m1 - n1);
            ls0 *= a0; ls1 *= a1;
            #pragma unroll
            for (int dt = 0; dt < 4; ++dt) {
                oacc[dt][0] *= a0;
                oacc[dt][1] *= a1;
            }
            m0 = n0; m1 = n1;
        }

        float ps0 = 0.0f, ps1 = 0.0f;
        s16x4 pb[4][2];
        #pragma unroll
        for (int jt = 0; jt < 4; ++jt) {
            #pragma unroll
            for (int r = 0; r < 4; ++r) {
                const float e0 = fast_exp2(sf[jt][0][r] - m0);
                ps0 += e0; pb[jt][0][r] = f2bf(e0);
                const float e1 = fast_exp2(sf[jt][1][r] - m1);
                ps1 += e1; pb[jt][1][r] = f2bf(e1);
            }
        }
        ls0 += ps0; ls1 += ps1;

        // --- O^T += V^T P^T (V fragment shared by both qb) ---
        #pragma unroll
        for (int dt = 0; dt < 4; ++dt) {
            const int rv = dt * 16 + col;
            const short* vrow = &Vlds[cur][rv * 64];
            #pragma unroll
            for (int jt = 0; jt < 4; ++jt) {
                const int slot = (jt * 2 + (g >> 1)) ^ (rv & 7);
                const s16x4 a = *reinterpret_cast<const s16x4*>(
                    vrow + slot * 8 + (g & 1) * 4);
                oacc[dt][0] = mfma16(a, pb[jt][0], oacc[dt][0]);
                oacc[dt][1] = mfma16(a, pb[jt][1], oacc[dt][1]);
            }
        }

        if (tt < 7) {
            *reinterpret_cast<s16x8*>(&Klds[cur ^ 1][sr * 64 + swz]) = kreg;
            *reinterpret_cast<s16x8*>(&Vlds[cur ^ 1][sr * 64 + swz]) = vreg;
        }
        __syncthreads();
    }

    ls0 += __shfl_xor(ls0, 16); ls0 += __shfl_xor(ls0, 32);
    ls1 += __shfl_xor(ls1, 16); ls1 += __shfl_xor(ls1, 32);

    // PO[sp][b][d][q] bf16
    short* pob = PO + ((size_t)sp * 4 + b) * 64 * 4096;
    #pragma unroll
    for (int dt = 0; dt < 4; ++dt) {
        #pragma unroll
        for (int r = 0; r < 4; ++r) {
            const int d = dt * 16 + 4 * g + r;
            pob[(size_t)d * 4096 + qbase + col]      = f2bf(oacc[dt][0][r]);
            pob[(size_t)d * 4096 + qbase + 16 + col] = f2bf(oacc[dt][1][r]);
        }
    }
    if (lane < 16) {
        const size_t mi = ((size_t)sp * 4 + b) * 4096 + qbase + lane;
        PM[mi] = m0; PM[mi + 16] = m1;
        PL[mi] = ls0; PL[mi + 16] = ls1;
    }
}

// -------------------------------------------------------------------------
// Kernel 3: combine 8 KV-split partials + residual. Coalesced.
// -------------------------------------------------------------------------
__global__ __launch_bounds__(256) void attn_combine(
    const short* __restrict__ PO, const float* __restrict__ PM,
    const float* __restrict__ PL, const float* __restrict__ x,
    float* __restrict__ out)
{
    const int idx = blockIdx.x * 256 + threadIdx.x;   // 262144
    const int q0  = (idx & 1023) * 4;
    const int d   = (idx >> 10) & 63;
    const int b   = idx >> 16;

    float mq[4] = {-1e30f, -1e30f, -1e30f, -1e30f};
    float pm[8][4];
    #pragma unroll
    for (int s = 0; s < 8; ++s) {
        const f32x4 pmb = *reinterpret_cast<const f32x4*>(
            PM + ((size_t)s * 4 + b) * 4096 + q0);
        #pragma unroll
        for (int i = 0; i < 4; ++i) {
            pm[s][i] = pmb[i];
            mq[i] = fmaxf(mq[i], pmb[i]);
        }
    }
    float lq[4] = {0.0f, 0.0f, 0.0f, 0.0f};
    float oq[4] = {0.0f, 0.0f, 0.0f, 0.0f};
    #pragma unroll
    for (int s = 0; s < 8; ++s) {
        const f32x4 plb = *reinterpret_cast<const f32x4*>(
            PL + ((size_t)s * 4 + b) * 4096 + q0);
        const s16x4 ov = *reinterpret_cast<const s16x4*>(
            PO + (((size_t)s * 4 + b) * 64 + d) * 4096 + q0);
        #pragma unroll
        for (int i = 0; i < 4; ++i) {
            const float sc = fast_exp2(pm[s][i] - mq[i]);
            lq[i] += plb[i] * sc;
            oq[i] = fmaf(bf2f(ov[i]), sc, oq[i]);
        }
    }
    const size_t ob = ((size_t)b * 64 + d) * 4096 + q0;
    const float4 xv = *reinterpret_cast<const float4*>(x + ob);
    float4 o4;
    o4.x = fmaf(oq[0], 1.0f / lq[0], xv.x);
    o4.y = fmaf(oq[1], 1.0f / lq[1], xv.y);
    o4.z = fmaf(oq[2], 1.0f / lq[2], xv.z);
    o4.w = fmaf(oq[3], 1.0f / lq[3], xv.w);
    *reinterpret_cast<float4*>(out + ob) = o4;
}

extern "C" void kernel_launch(void* const* d_in, const int* in_sizes, int n_in,
                              void* d_out, int out_size, void* d_ws, size_t ws_size,
                              hipStream_t stream) {
    const float* x  = (const float*)d_in[0];
    const float* wq = (const float*)d_in[1];
    const float* bq = (const float*)d_in[2];
    const float* wk = (const float*)d_in[3];
    const float* bk = (const float*)d_in[4];
    const float* wv = (const float*)d_in[5];
    const float* bv = (const float*)d_in[6];
    float* out = (float*)d_out;

    short* Qg  = reinterpret_cast<short*>(d_ws);   // [4][4096][64]  2MB
    short* Kg  = Qg  + (size_t)4 * 4096 * 64;      // [4][4096][64]  2MB
    short* Vtg = Kg  + (size_t)4 * 4096 * 64;      // [4][64][4096]  2MB
    short* PO  = Vtg + (size_t)4 * 4096 * 64;      // [8][4][64][4096] 16MB
    float* PM  = reinterpret_cast<float*>(PO + (size_t)8 * 4 * 64 * 4096); // 512KB
    float* PL  = PM + (size_t)8 * 4 * 4096;                                // 512KB

    qkv_proj<<<dim3(256), dim3(512), 0, stream>>>(x, wq, bq, wk, bk, wv, bv, Qg, Kg, Vtg);
    attn_part<<<dim3(512), dim3(512), 0, stream>>>(Qg, Kg, Vtg, PO, PM, PL);
    attn_combine<<<dim3(1024), dim3(256), 0, stream>>>(PO, PM, PL, x, out);
}

// Round 6
// 52.617 us; speedup vs baseline: 1.0950x; 1.0950x over previous
//
#include <hip/hip_runtime.h>
#include <hip/hip_bf16.h>

typedef float    f32x4  __attribute__((ext_vector_type(4)));
typedef float    f32x16 __attribute__((ext_vector_type(16)));
typedef short    s16x4  __attribute__((ext_vector_type(4)));
typedef short    s16x8  __attribute__((ext_vector_type(8)));
typedef unsigned u32x4  __attribute__((ext_vector_type(4)));
typedef __bf16   bf16x8 __attribute__((ext_vector_type(8)));

#define DEVI __device__ __forceinline__

DEVI short f2bf(float f) {
    unsigned u = __builtin_bit_cast(unsigned, f);
    u += 0x8000u;
    return (short)(u >> 16);
}
DEVI float bf2f(short s) {
    return __builtin_bit_cast(float, ((unsigned)(unsigned short)s) << 16);
}
DEVI unsigned pack2bf(float a, float b) {
    return (unsigned)(unsigned short)f2bf(a) | ((unsigned)(unsigned short)f2bf(b) << 16);
}

DEVI float fast_exp2(float x) {
#if defined(__HIP_DEVICE_COMPILE__) && __has_builtin(__builtin_amdgcn_exp2f)
    return __builtin_amdgcn_exp2f(x);
#else
    return exp2f(x);
#endif
}

DEVI f32x4 mfma32(s16x8 a, s16x8 b, f32x4 c) {
#if defined(__HIP_DEVICE_COMPILE__) && __has_builtin(__builtin_amdgcn_mfma_f32_16x16x32_bf16)
    return __builtin_amdgcn_mfma_f32_16x16x32_bf16(
        __builtin_bit_cast(bf16x8, a), __builtin_bit_cast(bf16x8, b), c, 0, 0, 0);
#else
    asm volatile("v_mfma_f32_16x16x32_bf16 %0, %1, %2, %0" : "+v"(c) : "v"(a), "v"(b));
    return c;
#endif
}

DEVI f32x16 mfma3216(s16x8 a, s16x8 b, f32x16 c) {
#if defined(__HIP_DEVICE_COMPILE__) && __has_builtin(__builtin_amdgcn_mfma_f32_32x32x16_bf16)
    return __builtin_amdgcn_mfma_f32_32x32x16_bf16(
        __builtin_bit_cast(bf16x8, a), __builtin_bit_cast(bf16x8, b), c, 0, 0, 0);
#else
    asm volatile("v_mfma_f32_32x32x16_bf16 %0, %1, %2, %0" : "+v"(c) : "v"(a), "v"(b));
    return c;
#endif
}

DEVI void setprio1() {
#if defined(__HIP_DEVICE_COMPILE__)
    __builtin_amdgcn_s_setprio(1);
#endif
}
DEVI void setprio0() {
#if defined(__HIP_DEVICE_COMPILE__)
    __builtin_amdgcn_s_setprio(0);
#endif
}

// -------------------------------------------------------------------------
// Kernel 1: QKV projection via MFMA (unchanged, working, ~3.5us).
//   Qg/Kg: [4][4096][64] bf16 (Q pre-scaled by log2(e)/8)
//   Vtg:   [4][64][4096] bf16
// -------------------------------------------------------------------------
__global__ __launch_bounds__(512) void qkv_proj(
    const float* __restrict__ x,
    const float* __restrict__ wq, const float* __restrict__ bq,
    const float* __restrict__ wk, const float* __restrict__ bk,
    const float* __restrict__ wv, const float* __restrict__ bv,
    short* __restrict__ Qg, short* __restrict__ Kg, short* __restrict__ Vtg)
{
    __shared__ short Xt[64 * 64];   // [l][c], slot-swizzled

    const int b  = blockIdx.x >> 6;
    const int l0 = (blockIdx.x & 63) * 64;
    const int t  = threadIdx.x;
    const float QS = 0.18033688011112042f;   // log2(e)/sqrt(64)

    {
        const int c  = t & 63;
        const int lh = (t >> 6) * 8;
        const float* xr = x + ((size_t)b * 64 + c) * 4096 + l0 + lh;
        const float4 x0 = *reinterpret_cast<const float4*>(xr);
        const float4 x1 = *reinterpret_cast<const float4*>(xr + 4);
        float xv[8] = {x0.x, x0.y, x0.z, x0.w, x1.x, x1.y, x1.z, x1.w};
        #pragma unroll
        for (int i = 0; i < 8; ++i) {
            const int l = lh + i;
            Xt[l * 64 + (((c >> 3) ^ (l & 7)) * 8) + (c & 7)] = f2bf(xv[i]);
        }
    }

    const int lane = t & 63, w = t >> 6;
    const int g = lane >> 4, col = lane & 15;
    const int o0 = (w & 3) * 16;
    const int h  = w >> 2;

    s16x8 wqf[2], wkf[2], wvf[2];
    #pragma unroll
    for (int kc = 0; kc < 2; ++kc) {
        const int cb = 8 * g + 32 * kc;
        const float4 q0 = *reinterpret_cast<const float4*>(wq + (o0 + col) * 64 + cb);
        const float4 q1 = *reinterpret_cast<const float4*>(wq + (o0 + col) * 64 + cb + 4);
        const float4 k0 = *reinterpret_cast<const float4*>(wk + (o0 + col) * 64 + cb);
        const float4 k1 = *reinterpret_cast<const float4*>(wk + (o0 + col) * 64 + cb + 4);
        const float4 v0 = *reinterpret_cast<const float4*>(wv + (o0 + col) * 64 + cb);
        const float4 v1 = *reinterpret_cast<const float4*>(wv + (o0 + col) * 64 + cb + 4);
        wqf[kc][0] = f2bf(q0.x * QS); wqf[kc][1] = f2bf(q0.y * QS);
        wqf[kc][2] = f2bf(q0.z * QS); wqf[kc][3] = f2bf(q0.w * QS);
        wqf[kc][4] = f2bf(q1.x * QS); wqf[kc][5] = f2bf(q1.y * QS);
        wqf[kc][6] = f2bf(q1.z * QS); wqf[kc][7] = f2bf(q1.w * QS);
        wkf[kc][0] = f2bf(k0.x); wkf[kc][1] = f2bf(k0.y);
        wkf[kc][2] = f2bf(k0.z); wkf[kc][3] = f2bf(k0.w);
        wkf[kc][4] = f2bf(k1.x); wkf[kc][5] = f2bf(k1.y);
        wkf[kc][6] = f2bf(k1.z); wkf[kc][7] = f2bf(k1.w);
        wvf[kc][0] = f2bf(v0.x); wvf[kc][1] = f2bf(v0.y);
        wvf[kc][2] = f2bf(v0.z); wvf[kc][3] = f2bf(v0.w);
        wvf[kc][4] = f2bf(v1.x); wvf[kc][5] = f2bf(v1.y);
        wvf[kc][6] = f2bf(v1.z); wvf[kc][7] = f2bf(v1.w);
    }
    const f32x4 bq4 = *reinterpret_cast<const f32x4*>(bq + o0 + 4 * g);
    const f32x4 bk4 = *reinterpret_cast<const f32x4*>(bk + o0 + 4 * g);
    const float bvs = bv[o0 + col];

    __syncthreads();

    #pragma unroll
    for (int li = 0; li < 2; ++li) {
        const int lt  = 2 * h + li;
        const int row = lt * 16 + col;
        const s16x8 xf0 = *reinterpret_cast<const s16x8*>(
            &Xt[row * 64 + ((g ^ (row & 7)) * 8)]);
        const s16x8 xf1 = *reinterpret_cast<const s16x8*>(
            &Xt[row * 64 + (((g + 4) ^ (row & 7)) * 8)]);

        f32x4 qa = bq4 * QS;
        qa = mfma32(wqf[0], xf0, qa);
        qa = mfma32(wqf[1], xf1, qa);
        f32x4 ka = bk4;
        ka = mfma32(wkf[0], xf0, ka);
        ka = mfma32(wkf[1], xf1, ka);
        f32x4 va = {bvs, bvs, bvs, bvs};
        va = mfma32(xf0, wvf[0], va);
        va = mfma32(xf1, wvf[1], va);

        s16x4 qs, ks;
        #pragma unroll
        for (int r = 0; r < 4; ++r) { qs[r] = f2bf(qa[r]); ks[r] = f2bf(ka[r]); }
        const size_t qkbase = ((size_t)b * 4096 + l0 + row) * 64 + o0 + 4 * g;
        *reinterpret_cast<s16x4*>(Qg + qkbase) = qs;
        *reinterpret_cast<s16x4*>(Kg + qkbase) = ks;

        s16x4 vs;
        #pragma unroll
        for (int r = 0; r < 4; ++r) vs[r] = f2bf(va[r]);
        *reinterpret_cast<s16x4*>(
            Vtg + ((size_t)b * 64 + o0 + col) * 4096 + l0 + lt * 16 + 4 * g) = vs;
    }
}

// -------------------------------------------------------------------------
// Kernel 2: flash attention partials, 32x32x16 MFMA structure.
// 512 blocks = 4 b x 16 q-tiles(256) x 8 KV-splits(512). 8 waves x 32 q.
// Swapped QK^T (mfma(K,Q) -> S^T[j][q]): lane q = lane&31 holds 16 j's
// -> softmax is 16-reg tree + ONE shfl_xor(32). P packs in-register and
// feeds PV's B-operand after one partner exchange (T12 pattern).
// K/V 64-row tiles double-buffered in swizzled LDS, one barrier/tile.
// Epilogue: O^T -> LDS (reusing K/V space) -> PO[q][d] coalesced 64B/lane.
// -------------------------------------------------------------------------
__global__ __launch_bounds__(512, 4) void attn_part(
    const short* __restrict__ Qg, const short* __restrict__ Kg,
    const short* __restrict__ Vtg,
    short* __restrict__ PO, float* __restrict__ PM, float* __restrict__ PL)
{
    __shared__ short SM[4 * 64 * 64];   // 32KB: K dbuf [0,1], V dbuf [2,3]; epilogue O
    __shared__ float ML[2][8][32];

    const int bid = blockIdx.x;
    const int wid = (bid & 7) * 64 + (bid >> 3);   // XCD-bijective (512 = 8x64)
    const int b   = wid >> 7;
    const int sp  = (wid >> 4) & 7;
    const int qt  = wid & 15;

    const int t    = threadIdx.x;
    const int w    = t >> 6;
    const int lane = t & 63;
    const int qi   = lane & 31;
    const int hi   = lane >> 5;

    const int qglob = qt * 256 + w * 32 + qi;

    // Q B-frags: qf[m] = Q[q][16m + 8hi .. +8)
    s16x8 qf[4];
    {
        const short* qp = Qg + ((size_t)b * 4096 + qglob) * 64 + 8 * hi;
        qf[0] = *reinterpret_cast<const s16x8*>(qp);
        qf[1] = *reinterpret_cast<const s16x8*>(qp + 16);
        qf[2] = *reinterpret_cast<const s16x8*>(qp + 32);
        qf[3] = *reinterpret_cast<const s16x8*>(qp + 48);
    }

    const short* Kb = Kg  + ((size_t)b * 4096 + sp * 512) * 64;
    const short* Vb = Vtg + (size_t)b * 64 * 4096 + sp * 512;

    // staging: thread stages one 16B K-chunk + one 16B V-chunk per tile
    const int sr  = t >> 3;
    const int sc  = t & 7;
    const int swz = (sc ^ (sr & 7)) * 8;
    const short* kg = Kb + sr * 64 + sc * 8;
    const short* vg = Vb + (size_t)sr * 4096 + sc * 8;

    s16x8 kreg = *reinterpret_cast<const s16x8*>(kg);
    s16x8 vreg = *reinterpret_cast<const s16x8*>(vg);
    *reinterpret_cast<s16x8*>(&SM[0 * 4096 + sr * 64 + swz]) = kreg;   // K buf0
    *reinterpret_cast<s16x8*>(&SM[2 * 4096 + sr * 64 + swz]) = vreg;   // V buf0
    __syncthreads();

    f32x16 oacc0 = {}, oacc1 = {};
    float mrun = -1e30f, lsum = 0.0f;

    const int rx  = qi & 7;   // swizzle key for this lane's K/V rows

    #pragma unroll 2
    for (int tt = 0; tt < 8; ++tt) {
        const int cur = tt & 1;
        const short* Kl = &SM[cur * 4096];
        const short* Vl = &SM[(2 + cur) * 4096];

        if (tt < 7) {   // T14: issue next tile's global loads early
            kreg = *reinterpret_cast<const s16x8*>(kg + (size_t)(tt + 1) * 4096);
            vreg = *reinterpret_cast<const s16x8*>(vg + (tt + 1) * 64);
        }

        #pragma unroll
        for (int jb = 0; jb < 2; ++jb) {
            // --- S^T[32 j][32 q] = K Q^T over d=64 (4 mfma) ---
            const short* krow = Kl + (jb * 32 + qi) * 64;
            f32x16 S = {};
            setprio1();
            #pragma unroll
            for (int m = 0; m < 4; ++m) {
                const s16x8 a = *reinterpret_cast<const s16x8*>(
                    krow + (((2 * m + hi) ^ rx) * 8));
                S = mfma3216(a, qf[m], S);
            }
            setprio0();

            // --- softmax: lane-local 16-reg tree + 1 partner exchange ---
            float mx = fmaxf(fmaxf(fmaxf(S[0], S[1]), fmaxf(S[2], S[3])),
                             fmaxf(fmaxf(S[4], S[5]), fmaxf(S[6], S[7])));
            mx = fmaxf(mx, fmaxf(fmaxf(fmaxf(S[8], S[9]), fmaxf(S[10], S[11])),
                                 fmaxf(fmaxf(S[12], S[13]), fmaxf(S[14], S[15]))));
            mx = fmaxf(mx, __shfl_xor(mx, 32));
            if (!__all(mx - mrun <= 8.0f)) {        // defer-max, thr 8 (exp2 dom)
                const float mn = fmaxf(mrun, mx);
                const float al = fast_exp2(mrun - mn);
                lsum *= al;
                oacc0 *= al;
                oacc1 *= al;
                mrun = mn;
            }

            float ps = 0.0f;
            unsigned Pu[8];
            #pragma unroll
            for (int i = 0; i < 8; ++i) {
                const float e0 = fast_exp2(S[2 * i]     - mrun);
                const float e1 = fast_exp2(S[2 * i + 1] - mrun);
                ps += e0 + e1;
                Pu[i] = pack2bf(e0, e1);
            }
            lsum += ps;

            unsigned X[8];
            #pragma unroll
            for (int i = 0; i < 8; ++i) X[i] = __shfl_xor(Pu[i], 32);

            // B-frags for the two 16-j slices of this 32-block
            u32x4 w0, w1;
            w0[0] = hi ? X[2]  : Pu[0]; w0[1] = hi ? X[3]  : Pu[1];
            w0[2] = hi ? Pu[2] : X[0];  w0[3] = hi ? Pu[3] : X[1];
            w1[0] = hi ? X[6]  : Pu[4]; w1[1] = hi ? X[7]  : Pu[5];
            w1[2] = hi ? Pu[6] : X[4];  w1[3] = hi ? Pu[7] : X[5];
            const s16x8 pf0 = __builtin_bit_cast(s16x8, w0);
            const s16x8 pf1 = __builtin_bit_cast(s16x8, w1);

            // --- O^T += V^T P^T (4 mfma: 2 d-blocks x 2 j-slices) ---
            const int t0 = jb * 2;
            const short* vr0 = Vl + qi * 64;
            const short* vr1 = Vl + (32 + qi) * 64;
            setprio1();
            {
                const s16x8 a00 = *reinterpret_cast<const s16x8*>(
                    vr0 + (((2 * t0 + hi) ^ rx) * 8));
                const s16x8 a10 = *reinterpret_cast<const s16x8*>(
                    vr1 + (((2 * t0 + hi) ^ rx) * 8));
                oacc0 = mfma3216(a00, pf0, oacc0);
                oacc1 = mfma3216(a10, pf0, oacc1);
                const s16x8 a01 = *reinterpret_cast<const s16x8*>(
                    vr0 + (((2 * t0 + 2 + hi) ^ rx) * 8));
                const s16x8 a11 = *reinterpret_cast<const s16x8*>(
                    vr1 + (((2 * t0 + 2 + hi) ^ rx) * 8));
                oacc0 = mfma3216(a01, pf1, oacc0);
                oacc1 = mfma3216(a11, pf1, oacc1);
            }
            setprio0();
        }

        if (tt < 7) {   // write next tile into the other buffers
            *reinterpret_cast<s16x8*>(&SM[(cur ^ 1) * 4096 + sr * 64 + swz]) = kreg;
            *reinterpret_cast<s16x8*>(&SM[(2 + (cur ^ 1)) * 4096 + sr * 64 + swz]) = vreg;
        }
        __syncthreads();
    }

    // total l for this q (both hi halves)
    const float ltot = lsum + __shfl_xor(lsum, 32);

    // --- epilogue: O^T -> LDS (K/V space now dead), then coalesced PO ---
    // Olds row rr = w*32 + q : 64 bf16 d-values, 16B-granule swizzled by q&7
    {
        short* O = SM;
        const int rr = w * 32 + qi;
        #pragma unroll
        for (int db = 0; db < 2; ++db) {
            const f32x16 oa = db ? oacc1 : oacc0;
            #pragma unroll
            for (int rq = 0; rq < 4; ++rq) {
                s16x4 pk;
                pk[0] = f2bf(oa[4 * rq + 0]); pk[1] = f2bf(oa[4 * rq + 1]);
                pk[2] = f2bf(oa[4 * rq + 2]); pk[3] = f2bf(oa[4 * rq + 3]);
                const int pg = (4 * db + rq) ^ (qi & 7);
                *reinterpret_cast<s16x4*>(&O[rr * 64 + pg * 8 + 4 * hi]) = pk;
            }
        }
        if (hi == 0) {
            ML[0][w][qi] = mrun;
            ML[1][w][qi] = ltot;
        }
    }
    __syncthreads();

    // PO[sp*4+b][qglob][64 d]: thread t -> row ql = t>>1, half ch = t&1 (32 d)
    {
        const short* O = SM;
        const int ql = t >> 1, ch = t & 1;
        const int qq = ql & 31;
        const short* orow = O + ql * 64;
        const s16x8 a0 = *reinterpret_cast<const s16x8*>(
            orow + (((4 * ch + 0) ^ (qq & 7)) * 8));
        const s16x8 a1 = *reinterpret_cast<const s16x8*>(
            orow + (((4 * ch + 1) ^ (qq & 7)) * 8));
        const s16x8 a2 = *reinterpret_cast<const s16x8*>(
            orow + (((4 * ch + 2) ^ (qq & 7)) * 8));
        const s16x8 a3 = *reinterpret_cast<const s16x8*>(
            orow + (((4 * ch + 3) ^ (qq & 7)) * 8));
        short* pp = PO + (((size_t)(sp * 4 + b) * 4096) + qt * 256 + ql) * 64 + ch * 32;
        *reinterpret_cast<s16x8*>(pp)      = a0;
        *reinterpret_cast<s16x8*>(pp + 8)  = a1;
        *reinterpret_cast<s16x8*>(pp + 16) = a2;
        *reinterpret_cast<s16x8*>(pp + 24) = a3;
        if (t < 256) {
            const size_t mi = (size_t)(sp * 4 + b) * 4096 + qt * 256 + t;
            PM[mi] = ML[0][t >> 5][t & 31];
            PL[mi] = ML[1][t >> 5][t & 31];
        }
    }
}

// -------------------------------------------------------------------------
// Kernel 3: combine 8 KV-split partials + residual, transpose via LDS.
// 256 blocks (b x 64-q tile) x 256 threads.
// Phase A: thread (ql, 16-d chunk): merge 8 partials -> T[d][ql] (padded).
// Phase B: thread (d, 16-q chunk): out[b][d][q] = T + x, coalesced.
// -------------------------------------------------------------------------
__global__ __launch_bounds__(256) void attn_combine(
    const short* __restrict__ PO, const float* __restrict__ PM,
    const float* __restrict__ PL, const float* __restrict__ x,
    float* __restrict__ out)
{
    __shared__ float T[64][68];

    const int b  = blockIdx.x >> 6;
    const int q0 = (blockIdx.x & 63) * 64;
    const int t  = threadIdx.x;

    {
        const int ql = t >> 2;
        const int dc = (t & 3) * 16;
        const int q  = q0 + ql;

        float pm[8];
        float M = -1e30f;
        #pragma unroll
        for (int s = 0; s < 8; ++s) {
            pm[s] = PM[(size_t)(s * 4 + b) * 4096 + q];
            M = fmaxf(M, pm[s]);
        }
        float L = 0.0f;
        float acc[16];
        #pragma unroll
        for (int i = 0; i < 16; ++i) acc[i] = 0.0f;
        #pragma unroll
        for (int s = 0; s < 8; ++s) {
            const float sc = fast_exp2(pm[s] - M);
            L += PL[(size_t)(s * 4 + b) * 4096 + q] * sc;
            const short* pp = PO + ((size_t)(s * 4 + b) * 4096 + q) * 64 + dc;
            const s16x8 o0 = *reinterpret_cast<const s16x8*>(pp);
            const s16x8 o1 = *reinterpret_cast<const s16x8*>(pp + 8);
            #pragma unroll
            for (int i = 0; i < 8; ++i) {
                acc[i]     = fmaf(bf2f(o0[i]), sc, acc[i]);
                acc[8 + i] = fmaf(bf2f(o1[i]), sc, acc[8 + i]);
            }
        }
        const float rL = 1.0f / L;
        #pragma unroll
        for (int i = 0; i < 16; ++i) T[dc + i][ql] = acc[i] * rL;
    }
    __syncthreads();
    {
        const int d  = t >> 2;
        const int qc = (t & 3) * 16;
        const size_t ob = ((size_t)b * 64 + d) * 4096 + q0 + qc;
        #pragma unroll
        for (int i = 0; i < 16; i += 4) {
            float4 xv = *reinterpret_cast<const float4*>(x + ob + i);
            float4 o4;
            o4.x = T[d][qc + i + 0] + xv.x;
            o4.y = T[d][qc + i + 1] + xv.y;
            o4.z = T[d][qc + i + 2] + xv.z;
            o4.w = T[d][qc + i + 3] + xv.w;
            *reinterpret_cast<float4*>(out + ob + i) = o4;
        }
    }
}

extern "C" void kernel_launch(void* const* d_in, const int* in_sizes, int n_in,
                              void* d_out, int out_size, void* d_ws, size_t ws_size,
                              hipStream_t stream) {
    const float* x  = (const float*)d_in[0];
    const float* wq = (const float*)d_in[1];
    const float* bq = (const float*)d_in[2];
    const float* wk = (const float*)d_in[3];
    const float* bk = (const float*)d_in[4];
    const float* wv = (const float*)d_in[5];
    const float* bv = (const float*)d_in[6];
    float* out = (float*)d_out;

    short* Qg  = reinterpret_cast<short*>(d_ws);   // [4][4096][64]  2MB
    short* Kg  = Qg  + (size_t)4 * 4096 * 64;      // [4][4096][64]  2MB
    short* Vtg = Kg  + (size_t)4 * 4096 * 64;      // [4][64][4096]  2MB
    short* PO  = Vtg + (size_t)4 * 4096 * 64;      // [8*4][4096][64] 16MB
    float* PM  = reinterpret_cast<float*>(PO + (size_t)32 * 4096 * 64); // 512KB
    float* PL  = PM + (size_t)32 * 4096;                                 // 512KB

    qkv_proj<<<dim3(256), dim3(512), 0, stream>>>(x, wq, bq, wk, bk, wv, bv, Qg, Kg, Vtg);
    attn_part<<<dim3(512), dim3(512), 0, stream>>>(Qg, Kg, Vtg, PO, PM, PL);
    attn_combine<<<dim3(256), dim3(256), 0, stream>>>(PO, PM, PL, x, out);
}